// Round 3
// baseline (1580.208 us; speedup 1.0000x reference)
//
#include <hip/hip_runtime.h>

// HOGCN: 2-layer GraphConv, N=50000, D=64, E=1.6M, fp32.
// Round 3: exact CSR sort (fill had 101MB partial-line writebacks, 120us;
// single-block scan over 50000) replaced by a chunked BUCKET sort (64 dst
// nodes per bucket). Aggregation accumulates a bucket in a 16KB LDS tile via
// ds_add_f32 (one LDS atomic per edge covers all 64 features). Bin-phase
// writes are sequential runs per (chunk,bucket) -> mostly full-line writebacks.

#define NN 50000
#define DD 64
#define EE 1600000
#define NPB 64                              // dst nodes per bucket
#define NB  ((NN + NPB - 1) / NPB)          // 782 buckets
#define CHUNK 8192                          // edges per bin block
#define NC ((EE + CHUNK - 1) / CHUNK)       // 196 chunks

// ---------- bucket-sort build ----------

// Per-chunk histogram over NB buckets (LDS atomics only).
__global__ __launch_bounds__(256) void hist_kernel(
    const int* __restrict__ ei, int* __restrict__ hist)
{
    __shared__ int lh[NB];
    const int c = blockIdx.x, t = threadIdx.x;
    for (int b = t; b < NB; b += 256) lh[b] = 0;
    __syncthreads();
    const int base = c * CHUNK;
#pragma unroll 4
    for (int i = 0; i < CHUNK; i += 256) {
        int e = base + i + t;
        if (e < EE) atomicAdd(&lh[ei[EE + e] >> 6], 1);   // dst row
    }
    __syncthreads();
    for (int b = t; b < NB; b += 256) hist[c * NB + b] = lh[b];
}

// Per-bucket totals (coalesced column sums).
__global__ __launch_bounds__(256) void btot_kernel(
    const int* __restrict__ hist, int* __restrict__ btot)
{
    int b = blockIdx.x * 256 + threadIdx.x;
    if (b >= NB) return;
    int s = 0;
    for (int c = 0; c < NC; ++c) s += hist[c * NB + b];
    btot[b] = s;
}

// Exclusive scan of NB bucket totals -> bbase[0..NB].
__global__ __launch_bounds__(1024) void scan_kernel(
    const int* __restrict__ btot, int* __restrict__ bbase)
{
    __shared__ int part[1024];
    const int t = threadIdx.x;
    part[t] = (t < NB) ? btot[t] : 0;
    __syncthreads();
    for (int off = 1; off < 1024; off <<= 1) {
        int v = (t >= off) ? part[t - off] : 0;
        __syncthreads();
        part[t] += v;
        __syncthreads();
    }
    if (t < NB) bbase[t + 1] = part[t];
    if (t == 0) bbase[0] = 0;
}

// Per-(chunk,bucket) start offsets (coalesced running sums down columns).
__global__ __launch_bounds__(256) void offs_kernel(
    const int* __restrict__ hist, const int* __restrict__ bbase,
    int* __restrict__ offs)
{
    int b = blockIdx.x * 256 + threadIdx.x;
    if (b >= NB) return;
    int r = bbase[b];
    for (int c = 0; c < NC; ++c) { offs[c * NB + b] = r; r += hist[c * NB + b]; }
}

// Bin edges into bucket-major order. packed.x = src | (dst&63)<<16, .y = w bits.
__global__ __launch_bounds__(256) void bin_kernel(
    const int* __restrict__ ei, const float* __restrict__ ew,
    const int* __restrict__ offs, int2* __restrict__ packed)
{
    __shared__ int cur[NB];
    const int c = blockIdx.x, t = threadIdx.x;
    for (int b = t; b < NB; b += 256) cur[b] = offs[c * NB + b];
    __syncthreads();
    const int base = c * CHUNK;
    for (int i = 0; i < CHUNK; i += 256) {
        int e = base + i + t;
        if (e < EE) {
            int src = ei[e];
            int dst = ei[EE + e];
            int wb  = __float_as_int(ew[e]);
            int pos = atomicAdd(&cur[dst >> 6], 1);
            packed[pos] = make_int2(src | ((dst & 63) << 16), wb);
        }
    }
}

// ---------- dense transforms ----------
// One wave per node; lane j holds W_rel/W_root row j in registers,
// broadcasts the node's x-row via __shfl. Z = x@Wrel^T, Y = x@Wroot^T + b.
__global__ __launch_bounds__(256) void transform_kernel(
    const float* __restrict__ xin,
    const float* __restrict__ Wrel, const float* __restrict__ Wroot,
    const float* __restrict__ bias,
    float* __restrict__ Z, float* __restrict__ Y)
{
    const int lane  = threadIdx.x & 63;
    const int gwave = blockIdx.x * 4 + (threadIdx.x >> 6);
    const int nwav  = gridDim.x * 4;

    float wrel[DD], wroot[DD];
#pragma unroll
    for (int k = 0; k < DD; k += 4) {
        float4 a = *(const float4*)(Wrel  + lane * DD + k);
        wrel[k] = a.x; wrel[k+1] = a.y; wrel[k+2] = a.z; wrel[k+3] = a.w;
        float4 b = *(const float4*)(Wroot + lane * DD + k);
        wroot[k] = b.x; wroot[k+1] = b.y; wroot[k+2] = b.z; wroot[k+3] = b.w;
    }
    const float bj = bias[lane];

    for (int i = gwave; i < NN; i += nwav) {
        float xv = xin[i * DD + lane];
        float ar = 0.0f, ao = 0.0f;
#pragma unroll
        for (int k = 0; k < DD; ++k) {
            float xk = __shfl(xv, k);
            ar = fmaf(xk, wrel[k],  ar);
            ao = fmaf(xk, wroot[k], ao);
        }
        Z[i * DD + lane] = ar;
        Y[i * DD + lane] = ao + bj;
    }
}

// ---------- bucket aggregation (fused relu epilogue) ----------
// One block per bucket of 64 dst nodes; acc tile in LDS; one ds_add_f32
// (all 64 features) per edge. H = relu(acc + Y).
__global__ __launch_bounds__(512) void aggregate_kernel(
    const float* __restrict__ Z, const float* __restrict__ Y,
    const int* __restrict__ bbase, const int2* __restrict__ packed,
    float* __restrict__ H)
{
    __shared__ float acc[NPB * DD];   // 16 KB
    const int t = threadIdx.x, lane = t & 63, w = t >> 6;   // 8 waves
    const int bk = blockIdx.x;

    for (int i = t; i < NPB * DD; i += 512) acc[i] = 0.0f;
    __syncthreads();

    const int start = bbase[bk], end = bbase[bk + 1];
    for (int e0 = start + w * 4; e0 < end; e0 += 32) {
        if (e0 + 3 < end) {            // wave-uniform branch
            int2 p0 = packed[e0];
            int2 p1 = packed[e0 + 1];
            int2 p2 = packed[e0 + 2];
            int2 p3 = packed[e0 + 3];
            float z0 = Z[(p0.x & 0xFFFF) * DD + lane];
            float z1 = Z[(p1.x & 0xFFFF) * DD + lane];
            float z2 = Z[(p2.x & 0xFFFF) * DD + lane];
            float z3 = Z[(p3.x & 0xFFFF) * DD + lane];
            atomicAdd(&acc[(p0.x >> 16) * DD + lane], __int_as_float(p0.y) * z0);
            atomicAdd(&acc[(p1.x >> 16) * DD + lane], __int_as_float(p1.y) * z1);
            atomicAdd(&acc[(p2.x >> 16) * DD + lane], __int_as_float(p2.y) * z2);
            atomicAdd(&acc[(p3.x >> 16) * DD + lane], __int_as_float(p3.y) * z3);
        } else {
            for (int e = e0; e < end; ++e) {
                int2 p = packed[e];
                float z = Z[(p.x & 0xFFFF) * DD + lane];
                atomicAdd(&acc[(p.x >> 16) * DD + lane], __int_as_float(p.y) * z);
            }
        }
    }
    __syncthreads();

    for (int l = w; l < NPB; l += 8) {
        int g = bk * NPB + l;
        if (g < NN) {
            int idx = g * DD + lane;
            H[idx] = fmaxf(acc[l * DD + lane] + Y[idx], 0.0f);
        }
    }
}

extern "C" void kernel_launch(void* const* d_in, const int* in_sizes, int n_in,
                              void* d_out, int out_size, void* d_ws, size_t ws_size,
                              hipStream_t stream)
{
    const float* x     = (const float*)d_in[0];
    const int*   ei    = (const int*)  d_in[1];
    const float* ew    = (const float*)d_in[2];
    const float* Wrel1 = (const float*)d_in[3];
    const float* brel1 = (const float*)d_in[4];
    const float* Wroot1= (const float*)d_in[5];
    const float* Wrel2 = (const float*)d_in[6];
    const float* brel2 = (const float*)d_in[7];
    const float* Wroot2= (const float*)d_in[8];

    float* out = (float*)d_out;                 // H1 (layer-1 out) and final

    const size_t ND = (size_t)NN * DD;
    float* Z      = (float*)d_ws;               // [N*D]
    float* Y      = Z + ND;                     // [N*D]
    int2*  packed = (int2*)(Y + ND);            // [E]
    int*   bbase  = (int*)(packed + EE);        // [NB+1]
    int*   btot   = bbase + NB + 1;             // [NB]
    // hist/offs are dead before transform_kernel writes Z -> alias onto Z.
    int*   hist   = (int*)Z;                    // [NC*NB]
    int*   offs   = hist + NC * NB;             // [NC*NB]

    // ---- bucket-sort build (graph identical for both layers) ----
    hist_kernel<<<NC, 256, 0, stream>>>(ei, hist);
    btot_kernel<<<(NB + 255) / 256, 256, 0, stream>>>(hist, btot);
    scan_kernel<<<1, 1024, 0, stream>>>(btot, bbase);
    offs_kernel<<<(NB + 255) / 256, 256, 0, stream>>>(hist, bbase, offs);
    bin_kernel<<<NC, 256, 0, stream>>>(ei, ew, offs, packed);

    // ---- layer 1 ----
    transform_kernel<<<1024, 256, 0, stream>>>(x, Wrel1, Wroot1, brel1, Z, Y);
    aggregate_kernel<<<NB, 512, 0, stream>>>(Z, Y, bbase, packed, out);

    // ---- layer 2 ----
    transform_kernel<<<1024, 256, 0, stream>>>(out, Wrel2, Wroot2, brel2, Z, Y);
    aggregate_kernel<<<NB, 512, 0, stream>>>(Z, Y, bbase, packed, out);
}

// Round 4
// 365.785 us; speedup vs baseline: 4.3200x; 4.3200x over previous
//
#include <hip/hip_runtime.h>

// HOGCN: 2-layer GraphConv, N=50000, D=64, E=1.6M, fp32.
// Round 4: round-3's bucket aggregation was latency-starved (6256 waves,
// VALUBusy 3.5%). Revert to round-2's wave-per-node register aggregation
// (50000 waves, 4-deep gather unroll) over an EXACT dst-sorted CSR, built
// without round-2's partial-line fill (101MB writebacks): bucket-bin by
// dst>>6 (sequential runs, full lines) then per-bucket LDS counting sort.

#define NN 50000
#define DD 64
#define EE 1600000
#define NPB 64                              // dst nodes per bucket
#define NB  ((NN + NPB - 1) / NPB)          // 782 buckets
#define CHUNK 8192                          // edges per bin block
#define NC ((EE + CHUNK - 1) / CHUNK)       // 196 chunks
#define CAP 6144                            // LDS staging per bucket (48 KB)

// ---------- phase A: bucket binning ----------

__global__ __launch_bounds__(256) void hist_kernel(
    const int* __restrict__ ei, int* __restrict__ hist)
{
    __shared__ int lh[NB];
    const int c = blockIdx.x, t = threadIdx.x;
    for (int b = t; b < NB; b += 256) lh[b] = 0;
    __syncthreads();
    const int base = c * CHUNK;
#pragma unroll 4
    for (int i = 0; i < CHUNK; i += 256) {
        int e = base + i + t;
        if (e < EE) atomicAdd(&lh[ei[EE + e] >> 6], 1);   // dst row
    }
    __syncthreads();
    for (int b = t; b < NB; b += 256) hist[c * NB + b] = lh[b];
}

__global__ __launch_bounds__(256) void btot_kernel(
    const int* __restrict__ hist, int* __restrict__ btot)
{
    int b = blockIdx.x * 256 + threadIdx.x;
    if (b >= NB) return;
    int s = 0;
    for (int c = 0; c < NC; ++c) s += hist[c * NB + b];
    btot[b] = s;
}

__global__ __launch_bounds__(1024) void scan_kernel(
    const int* __restrict__ btot, int* __restrict__ bbase)
{
    __shared__ int part[1024];
    const int t = threadIdx.x;
    part[t] = (t < NB) ? btot[t] : 0;
    __syncthreads();
    for (int off = 1; off < 1024; off <<= 1) {
        int v = (t >= off) ? part[t - off] : 0;
        __syncthreads();
        part[t] += v;
        __syncthreads();
    }
    if (t < NB) bbase[t + 1] = part[t];
    if (t == 0) bbase[0] = 0;
}

__global__ __launch_bounds__(256) void offs_kernel(
    const int* __restrict__ hist, const int* __restrict__ bbase,
    int* __restrict__ offs)
{
    int b = blockIdx.x * 256 + threadIdx.x;
    if (b >= NB) return;
    int r = bbase[b];
    for (int c = 0; c < NC; ++c) { offs[c * NB + b] = r; r += hist[c * NB + b]; }
}

// Bin edges bucket-major. packed_b.x = src | (dst&63)<<16, .y = weight bits.
// Writes are sequential runs per (chunk,bucket) -> mostly full-line.
__global__ __launch_bounds__(256) void bin_kernel(
    const int* __restrict__ ei, const float* __restrict__ ew,
    const int* __restrict__ offs, int2* __restrict__ packed_b)
{
    __shared__ int cur[NB];
    const int c = blockIdx.x, t = threadIdx.x;
    for (int b = t; b < NB; b += 256) cur[b] = offs[c * NB + b];
    __syncthreads();
    const int base = c * CHUNK;
    for (int i = 0; i < CHUNK; i += 256) {
        int e = base + i + t;
        if (e < EE) {
            int src = ei[e];
            int dst = ei[EE + e];
            int wb  = __float_as_int(ew[e]);
            int pos = atomicAdd(&cur[dst >> 6], 1);
            packed_b[pos] = make_int2(src | ((dst & 63) << 16), wb);
        }
    }
}

// ---------- phase B: per-bucket LDS counting sort -> exact CSR ----------
// One block per bucket: sequential read, sort by dst&63 through LDS staging,
// sequential write. Emits per-node offsets. Fallback to direct global
// scatter only if a bucket exceeds CAP (probability ~0 for random graphs).
__global__ __launch_bounds__(256) void sort_kernel(
    const int2* __restrict__ packed_b, const int* __restrict__ bbase,
    int2* __restrict__ packed_s, int* __restrict__ offsets)
{
    __shared__ int  cnt[NPB];
    __shared__ int  cur[NPB];
    __shared__ int2 stage[CAP];
    const int bk = blockIdx.x, t = threadIdx.x;
    const int start = bbase[bk], end = bbase[bk + 1], sz = end - start;

    if (t < NPB) cnt[t] = 0;
    __syncthreads();
    for (int i = t; i < sz; i += 256)
        atomicAdd(&cnt[(packed_b[start + i].x >> 16) & 63], 1);
    __syncthreads();

    if (t < 64) {                       // wave 0: exclusive scan of 64 counts
        int c = cnt[t];
        int v = c;
        for (int off = 1; off < 64; off <<= 1) {
            int u = __shfl_up(v, off);
            if (t >= off) v += u;
        }
        int ex = v - c;
        cur[t] = ex;
        int g = bk * NPB + t;
        if (g < NN) offsets[g] = start + ex;
    }
    if (bk == NB - 1 && t == 0) offsets[NN] = EE;
    __syncthreads();

    if (sz <= CAP) {
        for (int i = t; i < sz; i += 256) {
            int2 p = packed_b[start + i];
            int pos = atomicAdd(&cur[(p.x >> 16) & 63], 1);
            stage[pos] = make_int2(p.x & 0xFFFF, p.y);
        }
        __syncthreads();
        for (int i = t; i < sz; i += 256)
            packed_s[start + i] = stage[i];
    } else {                            // pathological bucket: direct scatter
        for (int i = t; i < sz; i += 256) {
            int2 p = packed_b[start + i];
            int pos = atomicAdd(&cur[(p.x >> 16) & 63], 1);
            packed_s[start + pos] = make_int2(p.x & 0xFFFF, p.y);
        }
    }
}

// ---------- dense transforms ----------
// One wave per node; lane j holds W_rel/W_root row j in registers,
// broadcasts the node's x-row via __shfl. Z = x@Wrel^T, Y = x@Wroot^T + b.
__global__ __launch_bounds__(256) void transform_kernel(
    const float* __restrict__ xin,
    const float* __restrict__ Wrel, const float* __restrict__ Wroot,
    const float* __restrict__ bias,
    float* __restrict__ Z, float* __restrict__ Y)
{
    const int lane  = threadIdx.x & 63;
    const int gwave = blockIdx.x * 4 + (threadIdx.x >> 6);
    const int nwav  = gridDim.x * 4;

    float wrel[DD], wroot[DD];
#pragma unroll
    for (int k = 0; k < DD; k += 4) {
        float4 a = *(const float4*)(Wrel  + lane * DD + k);
        wrel[k] = a.x; wrel[k+1] = a.y; wrel[k+2] = a.z; wrel[k+3] = a.w;
        float4 b = *(const float4*)(Wroot + lane * DD + k);
        wroot[k] = b.x; wroot[k+1] = b.y; wroot[k+2] = b.z; wroot[k+3] = b.w;
    }
    const float bj = bias[lane];

    for (int i = gwave; i < NN; i += nwav) {
        float xv = xin[i * DD + lane];
        float ar = 0.0f, ao = 0.0f;
#pragma unroll
        for (int k = 0; k < DD; ++k) {
            float xk = __shfl(xv, k);
            ar = fmaf(xk, wrel[k],  ar);
            ao = fmaf(xk, wroot[k], ao);
        }
        Z[i * DD + lane] = ar;
        Y[i * DD + lane] = ao + bj;
    }
}

// ---------- aggregation (fused relu epilogue) ----------
// One wave per dst node, lane = feature, 4-deep gather unroll for MLP.
__global__ __launch_bounds__(256) void aggregate_kernel(
    const float* __restrict__ Z, const float* __restrict__ Y,
    const int* __restrict__ offsets, const int2* __restrict__ packed,
    float* __restrict__ H)
{
    const int lane = threadIdx.x & 63;
    const int node = blockIdx.x * 4 + (threadIdx.x >> 6);
    if (node >= NN) return;

    const int b = offsets[node];
    const int e = offsets[node + 1];
    float acc = 0.0f;
    int i = b;
    for (; i + 4 <= e; i += 4) {
        int2 p0 = packed[i];
        int2 p1 = packed[i + 1];
        int2 p2 = packed[i + 2];
        int2 p3 = packed[i + 3];
        float z0 = Z[p0.x * DD + lane];
        float z1 = Z[p1.x * DD + lane];
        float z2 = Z[p2.x * DD + lane];
        float z3 = Z[p3.x * DD + lane];
        acc = fmaf(__int_as_float(p0.y), z0, acc);
        acc = fmaf(__int_as_float(p1.y), z1, acc);
        acc = fmaf(__int_as_float(p2.y), z2, acc);
        acc = fmaf(__int_as_float(p3.y), z3, acc);
    }
    for (; i < e; ++i) {
        int2 p = packed[i];
        acc = fmaf(__int_as_float(p.y), Z[p.x * DD + lane], acc);
    }
    H[node * DD + lane] = fmaxf(acc + Y[node * DD + lane], 0.0f);
}

extern "C" void kernel_launch(void* const* d_in, const int* in_sizes, int n_in,
                              void* d_out, int out_size, void* d_ws, size_t ws_size,
                              hipStream_t stream)
{
    const float* x     = (const float*)d_in[0];
    const int*   ei    = (const int*)  d_in[1];
    const float* ew    = (const float*)d_in[2];
    const float* Wrel1 = (const float*)d_in[3];
    const float* brel1 = (const float*)d_in[4];
    const float* Wroot1= (const float*)d_in[5];
    const float* Wrel2 = (const float*)d_in[6];
    const float* brel2 = (const float*)d_in[7];
    const float* Wroot2= (const float*)d_in[8];

    float* out = (float*)d_out;                 // H1 (layer-1 out) and final

    const size_t ND = (size_t)NN * DD;
    // persistent regions
    float* Z        = (float*)d_ws;             // [N*D]
    float* Y        = Z + ND;                   // [N*D]
    int2*  packed_s = (int2*)(Y + ND);          // [E] exact CSR (persists)
    int*   offsets  = (int*)(packed_s + EE);    // [N+1]
    int*   bbase    = offsets + NN + 1;         // [NB+1]
    int*   btot     = bbase + NB + 1;           // [NB]
    // build-phase temporaries, aliased onto regions dead during the build:
    int2*  packed_b = (int2*)Z;                 // [E] on Z+Y (dead until transform)
    int*   hist     = (int*)packed_s;           // [NC*NB] on packed_s (dead until sort)
    int*   offs     = hist + NC * NB;           // [NC*NB]

    // ---- build exact CSR (graph identical for both layers) ----
    hist_kernel<<<NC, 256, 0, stream>>>(ei, hist);
    btot_kernel<<<(NB + 255) / 256, 256, 0, stream>>>(hist, btot);
    scan_kernel<<<1, 1024, 0, stream>>>(btot, bbase);
    offs_kernel<<<(NB + 255) / 256, 256, 0, stream>>>(hist, bbase, offs);
    bin_kernel<<<NC, 256, 0, stream>>>(ei, ew, offs, packed_b);
    sort_kernel<<<NB, 256, 0, stream>>>(packed_b, bbase, packed_s, offsets);

    // ---- layer 1 ----
    transform_kernel<<<1024, 256, 0, stream>>>(x, Wrel1, Wroot1, brel1, Z, Y);
    aggregate_kernel<<<(NN + 3) / 4, 256, 0, stream>>>(Z, Y, offsets, packed_s, out);

    // ---- layer 2 ----
    transform_kernel<<<1024, 256, 0, stream>>>(out, Wrel2, Wroot2, brel2, Z, Y);
    aggregate_kernel<<<(NN + 3) / 4, 256, 0, stream>>>(Z, Y, offsets, packed_s, out);
}